// Round 4
// baseline (206.932 us; speedup 1.0000x reference)
//
#include <hip/hip_runtime.h>

// 5x5 normalized box blur, REFLECT_101, fp32, NCHW 32x3x512x512.
// Max-TLP formulation: one thread = one float4 output. 15 independent loads
// (5 rows x {float4 center + 2 float2 halo}), horizontal 5-sum in registers,
// direct 5-row vertical sum. No LDS, no serial per-thread loop, no ring
// buffer -> nothing to spill, nothing for the scheduler to serialize.
// Vertical 5x re-reads are absorbed by L1/L2; HBM sees compulsory traffic.

#define IMG_H 512
#define IMG_W 512
#define NF4   (IMG_W / 4)   // 128 float4-columns per row

struct F4 { float x, y, z, w; };
struct Raw { float4 b; float2 a, c; };

__global__ __launch_bounds__(256) void smooth_box5_flat(
    const float* __restrict__ in, float* __restrict__ out)
{
    const int tid   = blockIdx.x * 256 + threadIdx.x;
    const int c4    = tid & (NF4 - 1);        // float4-column 0..127
    const int y     = (tid >> 7) & (IMG_H - 1);
    const int plane = tid >> 16;              // / (128*512)

    const size_t planeOff = (size_t)plane * (IMG_H * IMG_W);
    const float* __restrict__ ip = in + planeOff;

    const int xb = c4 * 4;
    const bool left  = (c4 == 0);
    const bool right = (c4 == NF4 - 1);
    const int xa = left  ? 0         : xb - 2;   // clamped, 8B-aligned
    const int xc = right ? IMG_W - 8 : xb + 4;   // clamped, 8B-aligned

    // ---- 15 independent loads, batched before any arithmetic ----
    Raw p[5];
    #pragma unroll
    for (int k = 0; k < 5; ++k) {
        int ry = y + k - 2;
        ry = (ry < 0) ? -ry : ry;                        // REFLECT_101 top
        ry = (ry >= IMG_H) ? (2 * IMG_H - 2 - ry) : ry;  // REFLECT_101 bottom
        const float* row = ip + (size_t)ry * IMG_W;
        p[k].b = *(const float4*)(row + xb);
        p[k].a = *(const float2*)(row + xa);
        p[k].c = *(const float2*)(row + xc);
    }

    // ---- horizontal 5-sums + vertical accumulation ----
    F4 S = {0.f, 0.f, 0.f, 0.f};
    #pragma unroll
    for (int k = 0; k < 5; ++k) {
        const Raw& q = p[k];
        const float a2 = left  ? q.b.z : q.a.x;   // col xb-2 (reflect -> 2)
        const float a3 = left  ? q.b.y : q.a.y;   // col xb-1 (reflect -> 1)
        const float c0 = right ? q.b.z : q.c.x;   // col xb+4 (reflect -> 510)
        const float c1 = right ? q.b.y : q.c.y;   // col xb+5 (reflect -> 509)
        const float s = q.b.x + q.b.y + q.b.z + q.b.w;
        S.x += s - q.b.w + a2 + a3;
        S.y += s + a3;
        S.z += s + c0;
        S.w += s - q.b.x + c0 + c1;
    }

    const float inv = 0.2f * 0.2f;   // matches reference's two 1/5 passes
    float4 o;
    o.x = S.x * inv; o.y = S.y * inv; o.z = S.z * inv; o.w = S.w * inv;
    *(float4*)(out + planeOff + (size_t)y * IMG_W + xb) = o;
}

extern "C" void kernel_launch(void* const* d_in, const int* in_sizes, int n_in,
                              void* d_out, int out_size, void* d_ws, size_t ws_size,
                              hipStream_t stream) {
    const float* img = (const float*)d_in[0];
    float* out = (float*)d_out;
    // 32*3 planes * 512 rows * 128 float4-cols = 6,291,456 threads
    const int total = 96 * IMG_H * NF4;
    dim3 grid(total / 256);                  // 24576 blocks
    dim3 block(256);
    smooth_box5_flat<<<grid, block, 0, stream>>>(img, out);
}